// Round 18
// baseline (805.216 us; speedup 1.0000x reference)
//
#include <hip/hip_runtime.h>

// ---------------------------------------------------------------------------
// EnhancedGraphEncoder: 4-layer GCN + BN + ReLU + skip + global mean pool
// N=100000 nodes, E=1.6M edges (+self loops), dims 128->128->128->128->64.
// R13/R17 base: uint2 CSR {src,norm}, bf16 hW gather, PURE k_agg, ticketed
// k_stats@256, BN+ReLU+skip fused into GEMM A-operand, cursor-free fill.
// NEW: CSR fill partitioned by dst>>13 (13 ranges, ~1.1MB CSR window each,
// L2-resident) with segment-major block interleave so the P-fold edge-list
// re-scan is L2-deduped -- attacks the 102MB RFO write amplification that
// made k_fill_edges the 87us top cost.
// ---------------------------------------------------------------------------

typedef unsigned short u16;
typedef unsigned int u32;
typedef __attribute__((ext_vector_type(8))) short bf16x8;
typedef __attribute__((ext_vector_type(4))) float f32x4;

#define PSH 13   // dst partition shift: windows of 8192 nodes

__device__ __forceinline__ float bflo(u32 u) { return __uint_as_float(u << 16); }
__device__ __forceinline__ float bfhi(u32 u) { return __uint_as_float(u & 0xffff0000u); }
__device__ __forceinline__ u16 f2bf(float f) {
    u32 u = __float_as_uint(f);
    u32 r = u + 0x7fffu + ((u >> 16) & 1u);   // round-to-nearest-even
    return (u16)(r >> 16);
}
__device__ __forceinline__ u32 pack2(float a, float b) {
    return (u32)f2bf(a) | ((u32)f2bf(b) << 16);
}

// ------------------------- preprocessing kernels ---------------------------

__global__ void k_deg(const int* __restrict__ edst, int E, int* __restrict__ deg) {
    int e = blockIdx.x * blockDim.x + threadIdx.x;
    if (e < E) atomicAdd(&deg[edst[e]], 1);
}

__global__ void k_dinv(const int* __restrict__ deg, int n, float* __restrict__ dinv) {
    int i = blockIdx.x * blockDim.x + threadIdx.x;
    if (i < n) {
        int c = deg[i] + 1;  // + self loop
        dinv[i] = rsqrtf((float)c);
    }
}

__global__ void k_bsum(const int* __restrict__ deg, int n, int* __restrict__ bsum) {
    __shared__ int sd[256];
    int base = blockIdx.x * 1024;
    int end = base + 1024; if (end > n) end = n;
    int s = 0;
    for (int i = base + threadIdx.x; i < end; i += 256) s += deg[i] + 1;
    sd[threadIdx.x] = s;
    __syncthreads();
    for (int off = 128; off > 0; off >>= 1) {
        if (threadIdx.x < off) sd[threadIdx.x] += sd[threadIdx.x + off];
        __syncthreads();
    }
    if (threadIdx.x == 0) bsum[blockIdx.x] = sd[0];
}

__global__ void k_scanb(int* __restrict__ bsum, int B) {
    int run = 0;
    for (int i = 0; i < B; ++i) { int v = bsum[i]; bsum[i] = run; run += v; }
}

__global__ void k_offs(const int* __restrict__ deg, int n, const int* __restrict__ bsum,
                       int* __restrict__ offs) {
    __shared__ int sd[256];
    int base = blockIdx.x * 1024;
    int carry = bsum[blockIdx.x];
    for (int tile = 0; tile < 4; ++tile) {
        int i = base + tile * 256 + threadIdx.x;
        int v = (i < n) ? (deg[i] + 1) : 0;
        sd[threadIdx.x] = v;
        __syncthreads();
        int x = v;
        for (int off = 1; off < 256; off <<= 1) {
            int y = (threadIdx.x >= off) ? sd[threadIdx.x - off] : 0;
            __syncthreads();
            x += y;
            sd[threadIdx.x] = x;
            __syncthreads();
        }
        if (i < n) offs[i] = carry + x - v;
        if (i == n - 1) offs[n] = carry + x;
        carry += sd[255];
        __syncthreads();
    }
}

// Partitioned CSR fill: block = (seg, p); scans edge segment, keeps edges
// with dst>>PSH == p. Writes land in a ~1.1MB L2-resident CSR window;
// the P-fold edge re-scan is L2-deduped (same segment, concurrent blocks).
__global__ void k_fillp(const int* __restrict__ esrc, const int* __restrict__ edst,
                        int E, const float* __restrict__ dinv,
                        const int* __restrict__ offs, int* __restrict__ deg,
                        uint2* __restrict__ csre, int P, int segsz) {
    const int p = blockIdx.x % P;
    const int seg = blockIdx.x / P;
    const int lo = seg * segsz;
    int hi = lo + segsz; if (hi > E) hi = E;
    for (int e = lo + threadIdx.x; e < hi; e += 256) {
        const int d = edst[e];
        if ((d >> PSH) == p) {
            const int s = esrc[e];
            const int rank = atomicSub(&deg[d], 1) - 1;
            csre[offs[d] + rank] =
                make_uint2((u32)s, __float_as_uint(dinv[s] * dinv[d]));
        }
    }
}

// self loop goes in the last slot: offs[i+1]-1 (no atomics needed)
__global__ void k_fill_self(int n, const float* __restrict__ dinv,
                            const int* __restrict__ offs, uint2* __restrict__ csre) {
    int i = blockIdx.x * blockDim.x + threadIdx.x;
    if (i < n) {
        float dv = dinv[i];
        csre[offs[i + 1] - 1] = make_uint2((u32)i, __float_as_uint(dv * dv));
    }
}

// batch is sorted -> per-graph counts via binary search, no atomics
__global__ void k_gcnt_bs(const int* __restrict__ batch, int n, int* __restrict__ gcnt) {
    int g = threadIdx.x;
    if (g < 128) {
        int lo0 = 0, hi0 = n;
        while (lo0 < hi0) { int m = (lo0 + hi0) >> 1; if (batch[m] < g) lo0 = m + 1; else hi0 = m; }
        int lo1 = lo0, hi1 = n;
        while (lo1 < hi1) { int m = (lo1 + hi1) >> 1; if (batch[m] < g + 1) lo1 = m + 1; else hi1 = m; }
        gcnt[g] = lo1 - lo0;
    }
}

// ------------------ weight transpose+convert: W[128][F] -> Wt[F][128] ------

template <int FOUT>
__global__ void k_wt(const float* __restrict__ W, u16* __restrict__ Wt) {
    __shared__ u16 l[128 * (FOUT + 8)];
    for (int i = threadIdx.x; i < 128 * FOUT; i += 256) {
        int k = i / FOUT, nn = i % FOUT;
        l[k * (FOUT + 8) + nn] = f2bf(W[i]);
    }
    __syncthreads();
    for (int i = threadIdx.x; i < 128 * FOUT; i += 256) {
        int nn = i >> 7, k = i & 127;
        Wt[nn * 128 + k] = l[k * (FOUT + 8) + nn];
    }
}

// ------------------------------- MFMA GEMM ---------------------------------
// O[n,FOUT](bf16) = A[n,128] @ W[128,FOUT], Wt[FOUT][128] bf16.
// MODE 1: A = f32 x, converted on the fly (layer 0).
// MODE 2: A = relu(aggf*sc+sh)      (fused BN, no skip)
// MODE 3: A = relu(aggf*sc+sh) + sw*hprev   (fused BN+skip)
// STOREH: additionally materialize A (bf16) to hout (later skip src).

template <int FOUT, int MODE, bool STOREH>
__global__ __launch_bounds__(256) void k_gemm_mfma(const void* __restrict__ Ap,
                                                   const u16* __restrict__ hprev,
                                                   const float* __restrict__ coef,
                                                   const float* __restrict__ swp,
                                                   const u16* __restrict__ Wt,
                                                   u16* __restrict__ hout,
                                                   u16* __restrict__ O, int n) {
    constexpr int NT = FOUT / 16;
    const int lane = threadIdx.x & 63;
    const int wave = threadIdx.x >> 6;
    const int fr = lane & 15;
    const int fq = lane >> 4;
    const int rowbase = blockIdx.x * 64 + wave * 16;
    const int arow = rowbase + fr;
    const bool aok = arow < n;
    const float* af = (const float*)Ap + (size_t)arow * 128 + fq * 8;
    const u16* hp = (MODE == 3) ? hprev + (size_t)arow * 128 + fq * 8 : nullptr;
    const u16* wp = Wt + fr * 128 + fq * 8;
    float sw = 0.f;
    if constexpr (MODE == 3) sw = *swp;

    f32x4 acc[NT];
#pragma unroll
    for (int t = 0; t < NT; ++t)
#pragma unroll
        for (int q = 0; q < 4; ++q) acc[t][q] = 0.f;

#pragma unroll
    for (int kk = 0; kk < 4; ++kk) {
        bf16x8 a;
#pragma unroll
        for (int q = 0; q < 8; ++q) a[q] = 0;
        if (aok) {
            if constexpr (MODE == 1) {
                const float4 x0 = *(const float4*)(af + kk * 32);
                const float4 x1 = *(const float4*)(af + kk * 32 + 4);
                a[0] = (short)f2bf(x0.x); a[1] = (short)f2bf(x0.y);
                a[2] = (short)f2bf(x0.z); a[3] = (short)f2bf(x0.w);
                a[4] = (short)f2bf(x1.x); a[5] = (short)f2bf(x1.y);
                a[6] = (short)f2bf(x1.z); a[7] = (short)f2bf(x1.w);
            } else {
                const int k0 = kk * 32 + fq * 8;
                const float4 v0 = *(const float4*)(af + kk * 32);
                const float4 v1 = *(const float4*)(af + kk * 32 + 4);
                const float4 sc0 = *(const float4*)&coef[k0];
                const float4 sc1 = *(const float4*)&coef[k0 + 4];
                const float4 sh0 = *(const float4*)&coef[128 + k0];
                const float4 sh1 = *(const float4*)&coef[128 + k0 + 4];
                float r[8];
                r[0] = fmaxf(fmaf(v0.x, sc0.x, sh0.x), 0.f);
                r[1] = fmaxf(fmaf(v0.y, sc0.y, sh0.y), 0.f);
                r[2] = fmaxf(fmaf(v0.z, sc0.z, sh0.z), 0.f);
                r[3] = fmaxf(fmaf(v0.w, sc0.w, sh0.w), 0.f);
                r[4] = fmaxf(fmaf(v1.x, sc1.x, sh1.x), 0.f);
                r[5] = fmaxf(fmaf(v1.y, sc1.y, sh1.y), 0.f);
                r[6] = fmaxf(fmaf(v1.z, sc1.z, sh1.z), 0.f);
                r[7] = fmaxf(fmaf(v1.w, sc1.w, sh1.w), 0.f);
                if constexpr (MODE == 3) {
                    const uint4 pv = *(const uint4*)(hp + kk * 32);
                    r[0] = fmaf(sw, bflo(pv.x), r[0]); r[1] = fmaf(sw, bfhi(pv.x), r[1]);
                    r[2] = fmaf(sw, bflo(pv.y), r[2]); r[3] = fmaf(sw, bfhi(pv.y), r[3]);
                    r[4] = fmaf(sw, bflo(pv.z), r[4]); r[5] = fmaf(sw, bfhi(pv.z), r[5]);
                    r[6] = fmaf(sw, bflo(pv.w), r[6]); r[7] = fmaf(sw, bfhi(pv.w), r[7]);
                }
                uint4 o;
                o.x = pack2(r[0], r[1]);
                o.y = pack2(r[2], r[3]);
                o.z = pack2(r[4], r[5]);
                o.w = pack2(r[6], r[7]);
                a = *(const bf16x8*)&o;
                if constexpr (STOREH)
                    *(uint4*)&hout[(size_t)arow * 128 + k0] = o;
            }
        }
#pragma unroll
        for (int t = 0; t < NT; ++t) {
            bf16x8 b = *(const bf16x8*)(wp + t * 16 * 128 + kk * 32);
            acc[t] = __builtin_amdgcn_mfma_f32_16x16x32_bf16(a, b, acc[t], 0, 0, 0);
        }
    }
#pragma unroll
    for (int i = 0; i < 4; ++i) {
        const int row = rowbase + fq * 4 + i;
        if (row < n) {
#pragma unroll
            for (int t = 0; t < NT; ++t)
                O[(size_t)row * FOUT + t * 16 + fr] = f2bf(acc[t][i]);
        }
    }
}

// ---------------------------- aggregation ----------------------------------
// agg[d,f](f32) = sum_{e: dst=d} hW[src_e, f](bf16) * norm_e  (CSR by dst)
// PURE gather (R12/R13-proven): low VGPR -> high occupancy.

template <int F>
__global__ __launch_bounds__(256) void k_agg(const u16* __restrict__ hW,
                                             const uint2* __restrict__ csre,
                                             const int* __restrict__ offs,
                                             float* __restrict__ agg, int n) {
    constexpr int TPN = F / 8;       // lanes per node (16 or 8)
    constexpr int NPB = 256 / TPN;   // nodes per block (16 or 32)
    const int lane = threadIdx.x % TPN;
    const int sub = threadIdx.x / TPN;
    const int fbase = lane * 8;

    for (int node = blockIdx.x * NPB + sub; node < n; node += gridDim.x * NPB) {
        const int beg = offs[node];
        const int end = offs[node + 1];
        float4 b0 = make_float4(0.f, 0.f, 0.f, 0.f);
        float4 b1 = make_float4(0.f, 0.f, 0.f, 0.f);
        float4 c0 = make_float4(0.f, 0.f, 0.f, 0.f);
        float4 c1 = make_float4(0.f, 0.f, 0.f, 0.f);
        int j = beg;
        for (; j + 8 <= end; j += 8) {
            uint2 ei[8];
#pragma unroll
            for (int q = 0; q < 8; ++q) ei[q] = csre[j + q];
            uint4 v[8];
#pragma unroll
            for (int q = 0; q < 8; ++q)
                v[q] = *(const uint4*)&hW[(size_t)ei[q].x * F + fbase];
#pragma unroll
            for (int q = 0; q < 8; ++q) {
                const float w = __uint_as_float(ei[q].y);
                if (q & 1) {
                    c0.x = fmaf(bflo(v[q].x), w, c0.x); c0.y = fmaf(bfhi(v[q].x), w, c0.y);
                    c0.z = fmaf(bflo(v[q].y), w, c0.z); c0.w = fmaf(bfhi(v[q].y), w, c0.w);
                    c1.x = fmaf(bflo(v[q].z), w, c1.x); c1.y = fmaf(bfhi(v[q].z), w, c1.y);
                    c1.z = fmaf(bflo(v[q].w), w, c1.z); c1.w = fmaf(bfhi(v[q].w), w, c1.w);
                } else {
                    b0.x = fmaf(bflo(v[q].x), w, b0.x); b0.y = fmaf(bfhi(v[q].x), w, b0.y);
                    b0.z = fmaf(bflo(v[q].y), w, b0.z); b0.w = fmaf(bfhi(v[q].y), w, b0.w);
                    b1.x = fmaf(bflo(v[q].z), w, b1.x); b1.y = fmaf(bfhi(v[q].z), w, b1.y);
                    b1.z = fmaf(bflo(v[q].w), w, b1.z); b1.w = fmaf(bfhi(v[q].w), w, b1.w);
                }
            }
        }
        for (; j < end; ++j) {
            const uint2 e0 = csre[j];
            const float w = __uint_as_float(e0.y);
            const uint4 v0 = *(const uint4*)&hW[(size_t)e0.x * F + fbase];
            b0.x = fmaf(bflo(v0.x), w, b0.x); b0.y = fmaf(bfhi(v0.x), w, b0.y);
            b0.z = fmaf(bflo(v0.y), w, b0.z); b0.w = fmaf(bfhi(v0.y), w, b0.w);
            b1.x = fmaf(bflo(v0.z), w, b1.x); b1.y = fmaf(bfhi(v0.z), w, b1.y);
            b1.z = fmaf(bflo(v0.w), w, b1.z); b1.w = fmaf(bfhi(v0.w), w, b1.w);
        }
        b0.x += c0.x; b0.y += c0.y; b0.z += c0.z; b0.w += c0.w;
        b1.x += c1.x; b1.y += c1.y; b1.z += c1.z; b1.w += c1.w;
        __builtin_nontemporal_store(*(const f32x4*)&b0,
                                    (f32x4*)&agg[(size_t)node * F + fbase]);
        __builtin_nontemporal_store(*(const f32x4*)&b1,
                                    (f32x4*)&agg[(size_t)node * F + fbase + 4]);
    }
}

// --------------------- BN stats + coef (fused, ticketed) -------------------

template <int F>
__global__ __launch_bounds__(256) void k_stats(const float* __restrict__ aggf,
                                               float* __restrict__ stats,
                                               int* __restrict__ ticket,
                                               const float* __restrict__ g,
                                               const float* __restrict__ be,
                                               float* __restrict__ coef,
                                               float inv_n, int n8) {
    constexpr int TPR = F / 8;
    const int tid0 = blockIdx.x * 256 + threadIdx.x;
    float s[8], q[8];
#pragma unroll
    for (int k = 0; k < 8; ++k) { s[k] = 0.f; q[k] = 0.f; }
    for (int i = tid0; i < n8; i += gridDim.x * 256) {
        const float4 v0 = *(const float4*)&aggf[(size_t)i * 8];
        const float4 v1 = *(const float4*)&aggf[(size_t)i * 8 + 4];
        s[0] += v0.x; s[1] += v0.y; s[2] += v0.z; s[3] += v0.w;
        s[4] += v1.x; s[5] += v1.y; s[6] += v1.z; s[7] += v1.w;
        q[0] = fmaf(v0.x, v0.x, q[0]); q[1] = fmaf(v0.y, v0.y, q[1]);
        q[2] = fmaf(v0.z, v0.z, q[2]); q[3] = fmaf(v0.w, v0.w, q[3]);
        q[4] = fmaf(v1.x, v1.x, q[4]); q[5] = fmaf(v1.y, v1.y, q[5]);
        q[6] = fmaf(v1.z, v1.z, q[6]); q[7] = fmaf(v1.w, v1.w, q[7]);
    }
#pragma unroll
    for (int m = TPR; m < 64; m <<= 1) {
#pragma unroll
        for (int k = 0; k < 8; ++k) {
            s[k] += __shfl_xor(s[k], m);
            q[k] += __shfl_xor(q[k], m);
        }
    }
    __shared__ float sred[2][4][TPR * 8];
    const int w = threadIdx.x >> 6;
    const int l64 = threadIdx.x & 63;
    if (l64 < TPR) {
#pragma unroll
        for (int k = 0; k < 8; ++k) {
            sred[0][w][l64 * 8 + k] = s[k];
            sred[1][w][l64 * 8 + k] = q[k];
        }
    }
    __syncthreads();
    if (threadIdx.x < TPR * 8) {
        float a = sred[0][0][threadIdx.x] + sred[0][1][threadIdx.x] +
                  sred[0][2][threadIdx.x] + sred[0][3][threadIdx.x];
        float b = sred[1][0][threadIdx.x] + sred[1][1][threadIdx.x] +
                  sred[1][2][threadIdx.x] + sred[1][3][threadIdx.x];
        const int ff = threadIdx.x & (F - 1);
        atomicAdd(&stats[ff], a);
        atomicAdd(&stats[F + ff], b);
    }
    __threadfence();
    __shared__ int last;
    if (threadIdx.x == 0) last = (atomicAdd(ticket, 1) == (int)gridDim.x - 1) ? 1 : 0;
    __syncthreads();
    if (last) {
        if (threadIdx.x < F) {
            const int f = threadIdx.x;
            float sum = atomicAdd(&stats[f], 0.f);
            float ssq = atomicAdd(&stats[F + f], 0.f);
            float mean = sum * inv_n;
            float var = fmaxf(ssq * inv_n - mean * mean, 0.f);
            float sc = g[f] * rsqrtf(var + 1e-5f);
            coef[f] = sc;
            coef[F + f] = be[f] - mean * sc;
        }
    }
}

// ----------------------- layer-3 BN + mean pool -----------------------------

__global__ __launch_bounds__(256) void k_bnpool(const float* __restrict__ C,
                                                const int* __restrict__ batch,
                                                const float* __restrict__ coef,
                                                float* __restrict__ out, int n,
                                                int chunk) {
    __shared__ float pool[128 * 64];
    for (int i = threadIdx.x; i < 128 * 64; i += 256) pool[i] = 0.f;
    __syncthreads();
    const int f = threadIdx.x & 63;
    const int sub = threadIdx.x >> 6;
    const float sc = coef[f];
    const float sh = coef[64 + f];
    const int lo = blockIdx.x * chunk;
    int hi = lo + chunk; if (hi > n) hi = n;
    for (int node = lo + sub; node < hi; node += 4) {
        float v = fmaf(sc, C[(size_t)node * 64 + f], sh);
        int g = batch[node];
        atomicAdd(&pool[g * 64 + f], v);
    }
    __syncthreads();
    for (int i = threadIdx.x; i < 128 * 64; i += 256) {
        float v = pool[i];
        if (v != 0.f) atomicAdd(&out[i], v);
    }
}

__global__ void k_div(float* __restrict__ out, const int* __restrict__ gcnt, int total) {
    int i = blockIdx.x * blockDim.x + threadIdx.x;
    if (i < total) {
        int g = i >> 6;
        int c = gcnt[g];
        if (c < 1) c = 1;
        out[i] = out[i] / (float)c;
    }
}

// ------------------------------ launcher ------------------------------------

static inline size_t align256(size_t x) { return (x + 255) & ~(size_t)255; }

extern "C" void kernel_launch(void* const* d_in, const int* in_sizes, int n_in,
                              void* d_out, int out_size, void* d_ws, size_t ws_size,
                              hipStream_t stream) {
    const float* x    = (const float*)d_in[0];
    const int* ei     = (const int*)d_in[1];
    const int* batch  = (const int*)d_in[2];
    const float* W0   = (const float*)d_in[3];
    const float* g0   = (const float*)d_in[5];
    const float* be0  = (const float*)d_in[6];
    const float* W1   = (const float*)d_in[7];
    const float* g1   = (const float*)d_in[9];
    const float* be1  = (const float*)d_in[10];
    const float* W2   = (const float*)d_in[11];
    const float* g2   = (const float*)d_in[13];
    const float* be2  = (const float*)d_in[14];
    const float* W3   = (const float*)d_in[15];
    const float* g3   = (const float*)d_in[17];
    const float* be3  = (const float*)d_in[18];
    const float* swp  = (const float*)d_in[19];

    const int N = in_sizes[0] / 128;
    const int E = in_sizes[1] / 2;
    const int T = E + N;
    const int* esrc = ei;
    const int* edst = ei + E;

    char* p = (char*)d_ws;
    auto carve = [&](size_t bytes) -> char* {
        char* r = p;
        p += align256(bytes);
        return r;
    };
    int*   deg    = (int*)carve((size_t)N * 4);
    float* dinv   = (float*)carve((size_t)N * 4);
    int*   offs   = (int*)carve((size_t)(N + 1) * 4);
    int*   bsum   = (int*)carve(256 * 4);
    uint2* csre   = (uint2*)carve((size_t)T * 8);
    float* stats  = (float*)carve(4 * 256 * 4);
    float* coef   = (float*)carve(4 * 256 * 4);
    int*   ticket = (int*)carve(4 * 4);
    int*   gcnt   = (int*)carve(128 * 4);
    u16*   Wt0    = (u16*)carve(128 * 128 * 2);
    u16*   Wt1    = (u16*)carve(128 * 128 * 2);
    u16*   Wt2    = (u16*)carve(128 * 128 * 2);
    u16*   Wt3    = (u16*)carve(64 * 128 * 2);
    u16*   h0     = (u16*)carve((size_t)N * 128 * 2);
    u16*   h1     = (u16*)carve((size_t)N * 128 * 2);
    u16*   hWb    = (u16*)carve((size_t)N * 128 * 2);
    float* aggf   = (float*)carve((size_t)N * 128 * 4);

    hipMemsetAsync(deg, 0, (size_t)N * 4, stream);
    hipMemsetAsync(stats, 0, 4 * 256 * 4, stream);
    hipMemsetAsync(ticket, 0, 4 * 4, stream);
    hipMemsetAsync(d_out, 0, (size_t)out_size * 4, stream);

    // graph preprocessing
    const int EB = (E + 255) / 256;
    const int NB = (N + 255) / 256;
    const int B = (N + 1023) / 1024;
    const int P = (N + (1 << PSH) - 1) >> PSH;    // dst partitions (13)
    const int NSEG = 160;
    const int segsz = (E + NSEG - 1) / NSEG;
    k_deg<<<EB, 256, 0, stream>>>(edst, E, deg);
    k_dinv<<<NB, 256, 0, stream>>>(deg, N, dinv);
    k_bsum<<<B, 256, 0, stream>>>(deg, N, bsum);
    k_scanb<<<1, 1, 0, stream>>>(bsum, B);
    k_offs<<<B, 256, 0, stream>>>(deg, N, bsum, offs);
    k_fill_self<<<NB, 256, 0, stream>>>(N, dinv, offs, csre);
    k_fillp<<<NSEG * P, 256, 0, stream>>>(esrc, edst, E, dinv, offs, deg, csre,
                                          P, segsz);
    k_gcnt_bs<<<1, 128, 0, stream>>>(batch, N, gcnt);

    // weights -> bf16 transposed
    k_wt<128><<<1, 256, 0, stream>>>(W0, Wt0);
    k_wt<128><<<1, 256, 0, stream>>>(W1, Wt1);
    k_wt<128><<<1, 256, 0, stream>>>(W2, Wt2);
    k_wt<64><<<1, 256, 0, stream>>>(W3, Wt3);

    const float inv_n = 1.0f / (float)N;
    const int gemm_grid = (N + 63) / 64;
    const int chunk = (N + 255) / 256;
    const int n8_128 = N * 16;
    const int n8_64 = N * 8;

    // layer 0: x @ W0 (f32 in, cvt fused) -> agg -> stats+coef
    k_gemm_mfma<128, 1, false><<<gemm_grid, 256, 0, stream>>>(
        (const void*)x, nullptr, nullptr, nullptr, Wt0, nullptr, hWb, N);
    k_agg<128><<<2048, 256, 0, stream>>>(hWb, csre, offs, aggf, N);
    k_stats<128><<<256, 256, 0, stream>>>(aggf, stats + 0, ticket + 0, g0, be0,
                                          coef + 0, inv_n, n8_128);
    // layer 1: GEMM fuses bnapply_0 (no skip), stores h0; -> agg -> stats+coef
    k_gemm_mfma<128, 2, true><<<gemm_grid, 256, 0, stream>>>(
        (const void*)aggf, nullptr, coef + 0, nullptr, Wt1, h0, hWb, N);
    k_agg<128><<<2048, 256, 0, stream>>>(hWb, csre, offs, aggf, N);
    k_stats<128><<<256, 256, 0, stream>>>(aggf, stats + 256, ticket + 1, g1, be1,
                                          coef + 256, inv_n, n8_128);
    // layer 2: GEMM fuses bnapply_1 (skip from h0), stores h1; -> agg -> stats+coef
    k_gemm_mfma<128, 3, true><<<gemm_grid, 256, 0, stream>>>(
        (const void*)aggf, h0, coef + 256, swp, Wt2, h1, hWb, N);
    k_agg<128><<<2048, 256, 0, stream>>>(hWb, csre, offs, aggf, N);
    k_stats<128><<<256, 256, 0, stream>>>(aggf, stats + 512, ticket + 2, g2, be2,
                                          coef + 512, inv_n, n8_128);
    // layer 3: GEMM fuses bnapply_2 (skip from h1, no store); -> agg -> stats+coef
    k_gemm_mfma<64, 3, false><<<gemm_grid, 256, 0, stream>>>(
        (const void*)aggf, h1, coef + 512, swp, Wt3, nullptr, hWb, N);
    k_agg<64><<<2048, 256, 0, stream>>>(hWb, csre, offs, aggf, N);
    k_stats<64><<<256, 256, 0, stream>>>(aggf, stats + 768, ticket + 3, g3, be3,
                                         coef + 768, inv_n, n8_64);
    // BN + mean pool
    k_bnpool<<<256, 256, 0, stream>>>(aggf, batch, coef + 768, (float*)d_out, N, chunk);
    k_div<<<(out_size + 255) / 256, 256, 0, stream>>>((float*)d_out, gcnt, out_size);
}

// Round 19
// 781.901 us; speedup vs baseline: 1.0298x; 1.0298x over previous
//
#include <hip/hip_runtime.h>

// ---------------------------------------------------------------------------
// EnhancedGraphEncoder: 4-layer GCN + BN + ReLU + skip + global mean pool
// N=100000 nodes, E=1.6M edges (+self loops), dims 128->128->128->128->64.
// FINAL configuration (best measured 777us, R13): uint2 CSR {src,norm},
// bf16 hW gather, PURE k_agg (low VGPR -> high occupancy), ticketed
// k_stats@256 blocks, BN+ReLU+skip fused into GEMM A-operand, cursor-free
// CSR fill. Fill write-amplification (~100MB for 13.6MB payload) is
// cross-XCD structural (proven R14/R15/R17/R18) -- plain fill is its floor.
// ---------------------------------------------------------------------------

typedef unsigned short u16;
typedef unsigned int u32;
typedef __attribute__((ext_vector_type(8))) short bf16x8;
typedef __attribute__((ext_vector_type(4))) float f32x4;

__device__ __forceinline__ float bflo(u32 u) { return __uint_as_float(u << 16); }
__device__ __forceinline__ float bfhi(u32 u) { return __uint_as_float(u & 0xffff0000u); }
__device__ __forceinline__ u16 f2bf(float f) {
    u32 u = __float_as_uint(f);
    u32 r = u + 0x7fffu + ((u >> 16) & 1u);   // round-to-nearest-even
    return (u16)(r >> 16);
}
__device__ __forceinline__ u32 pack2(float a, float b) {
    return (u32)f2bf(a) | ((u32)f2bf(b) << 16);
}

// ------------------------- preprocessing kernels ---------------------------

__global__ void k_deg(const int* __restrict__ edst, int E, int* __restrict__ deg) {
    int e = blockIdx.x * blockDim.x + threadIdx.x;
    if (e < E) atomicAdd(&deg[edst[e]], 1);
}

__global__ void k_dinv(const int* __restrict__ deg, int n, float* __restrict__ dinv) {
    int i = blockIdx.x * blockDim.x + threadIdx.x;
    if (i < n) {
        int c = deg[i] + 1;  // + self loop
        dinv[i] = rsqrtf((float)c);
    }
}

__global__ void k_bsum(const int* __restrict__ deg, int n, int* __restrict__ bsum) {
    __shared__ int sd[256];
    int base = blockIdx.x * 1024;
    int end = base + 1024; if (end > n) end = n;
    int s = 0;
    for (int i = base + threadIdx.x; i < end; i += 256) s += deg[i] + 1;
    sd[threadIdx.x] = s;
    __syncthreads();
    for (int off = 128; off > 0; off >>= 1) {
        if (threadIdx.x < off) sd[threadIdx.x] += sd[threadIdx.x + off];
        __syncthreads();
    }
    if (threadIdx.x == 0) bsum[blockIdx.x] = sd[0];
}

__global__ void k_scanb(int* __restrict__ bsum, int B) {
    int run = 0;
    for (int i = 0; i < B; ++i) { int v = bsum[i]; bsum[i] = run; run += v; }
}

__global__ void k_offs(const int* __restrict__ deg, int n, const int* __restrict__ bsum,
                       int* __restrict__ offs) {
    __shared__ int sd[256];
    int base = blockIdx.x * 1024;
    int carry = bsum[blockIdx.x];
    for (int tile = 0; tile < 4; ++tile) {
        int i = base + tile * 256 + threadIdx.x;
        int v = (i < n) ? (deg[i] + 1) : 0;
        sd[threadIdx.x] = v;
        __syncthreads();
        int x = v;
        for (int off = 1; off < 256; off <<= 1) {
            int y = (threadIdx.x >= off) ? sd[threadIdx.x - off] : 0;
            __syncthreads();
            x += y;
            sd[threadIdx.x] = x;
            __syncthreads();
        }
        if (i < n) offs[i] = carry + x - v;
        if (i == n - 1) offs[n] = carry + x;
        carry += sd[255];
        __syncthreads();
    }
}

// CSR fill, cursor-free: rank = atomicSub(deg[d]) - 1 (deg consumed here).
__global__ void k_fill_edges(const int* __restrict__ esrc, const int* __restrict__ edst,
                             int E, const float* __restrict__ dinv,
                             const int* __restrict__ offs, int* __restrict__ deg,
                             uint2* __restrict__ csre) {
    int e = blockIdx.x * blockDim.x + threadIdx.x;
    if (e < E) {
        int s = esrc[e], d = edst[e];
        int rank = atomicSub(&deg[d], 1) - 1;
        csre[offs[d] + rank] = make_uint2((u32)s, __float_as_uint(dinv[s] * dinv[d]));
    }
}

// self loop goes in the last slot: offs[i+1]-1 (no atomics needed)
__global__ void k_fill_self(int n, const float* __restrict__ dinv,
                            const int* __restrict__ offs, uint2* __restrict__ csre) {
    int i = blockIdx.x * blockDim.x + threadIdx.x;
    if (i < n) {
        float dv = dinv[i];
        csre[offs[i + 1] - 1] = make_uint2((u32)i, __float_as_uint(dv * dv));
    }
}

// batch is sorted -> per-graph counts via binary search, no atomics
__global__ void k_gcnt_bs(const int* __restrict__ batch, int n, int* __restrict__ gcnt) {
    int g = threadIdx.x;
    if (g < 128) {
        int lo0 = 0, hi0 = n;
        while (lo0 < hi0) { int m = (lo0 + hi0) >> 1; if (batch[m] < g) lo0 = m + 1; else hi0 = m; }
        int lo1 = lo0, hi1 = n;
        while (lo1 < hi1) { int m = (lo1 + hi1) >> 1; if (batch[m] < g + 1) lo1 = m + 1; else hi1 = m; }
        gcnt[g] = lo1 - lo0;
    }
}

// ------------------ weight transpose+convert: W[128][F] -> Wt[F][128] ------

template <int FOUT>
__global__ void k_wt(const float* __restrict__ W, u16* __restrict__ Wt) {
    __shared__ u16 l[128 * (FOUT + 8)];
    for (int i = threadIdx.x; i < 128 * FOUT; i += 256) {
        int k = i / FOUT, nn = i % FOUT;
        l[k * (FOUT + 8) + nn] = f2bf(W[i]);
    }
    __syncthreads();
    for (int i = threadIdx.x; i < 128 * FOUT; i += 256) {
        int nn = i >> 7, k = i & 127;
        Wt[nn * 128 + k] = l[k * (FOUT + 8) + nn];
    }
}

// ------------------------------- MFMA GEMM ---------------------------------
// O[n,FOUT](bf16) = A[n,128] @ W[128,FOUT], Wt[FOUT][128] bf16.
// MODE 1: A = f32 x, converted on the fly (layer 0).
// MODE 2: A = relu(aggf*sc+sh)      (fused BN, no skip)
// MODE 3: A = relu(aggf*sc+sh) + sw*hprev   (fused BN+skip)
// STOREH: additionally materialize A (bf16) to hout (later skip src).

template <int FOUT, int MODE, bool STOREH>
__global__ __launch_bounds__(256) void k_gemm_mfma(const void* __restrict__ Ap,
                                                   const u16* __restrict__ hprev,
                                                   const float* __restrict__ coef,
                                                   const float* __restrict__ swp,
                                                   const u16* __restrict__ Wt,
                                                   u16* __restrict__ hout,
                                                   u16* __restrict__ O, int n) {
    constexpr int NT = FOUT / 16;
    const int lane = threadIdx.x & 63;
    const int wave = threadIdx.x >> 6;
    const int fr = lane & 15;
    const int fq = lane >> 4;
    const int rowbase = blockIdx.x * 64 + wave * 16;
    const int arow = rowbase + fr;
    const bool aok = arow < n;
    const float* af = (const float*)Ap + (size_t)arow * 128 + fq * 8;
    const u16* hp = (MODE == 3) ? hprev + (size_t)arow * 128 + fq * 8 : nullptr;
    const u16* wp = Wt + fr * 128 + fq * 8;
    float sw = 0.f;
    if constexpr (MODE == 3) sw = *swp;

    f32x4 acc[NT];
#pragma unroll
    for (int t = 0; t < NT; ++t)
#pragma unroll
        for (int q = 0; q < 4; ++q) acc[t][q] = 0.f;

#pragma unroll
    for (int kk = 0; kk < 4; ++kk) {
        bf16x8 a;
#pragma unroll
        for (int q = 0; q < 8; ++q) a[q] = 0;
        if (aok) {
            if constexpr (MODE == 1) {
                const float4 x0 = *(const float4*)(af + kk * 32);
                const float4 x1 = *(const float4*)(af + kk * 32 + 4);
                a[0] = (short)f2bf(x0.x); a[1] = (short)f2bf(x0.y);
                a[2] = (short)f2bf(x0.z); a[3] = (short)f2bf(x0.w);
                a[4] = (short)f2bf(x1.x); a[5] = (short)f2bf(x1.y);
                a[6] = (short)f2bf(x1.z); a[7] = (short)f2bf(x1.w);
            } else {
                const int k0 = kk * 32 + fq * 8;
                const float4 v0 = *(const float4*)(af + kk * 32);
                const float4 v1 = *(const float4*)(af + kk * 32 + 4);
                const float4 sc0 = *(const float4*)&coef[k0];
                const float4 sc1 = *(const float4*)&coef[k0 + 4];
                const float4 sh0 = *(const float4*)&coef[128 + k0];
                const float4 sh1 = *(const float4*)&coef[128 + k0 + 4];
                float r[8];
                r[0] = fmaxf(fmaf(v0.x, sc0.x, sh0.x), 0.f);
                r[1] = fmaxf(fmaf(v0.y, sc0.y, sh0.y), 0.f);
                r[2] = fmaxf(fmaf(v0.z, sc0.z, sh0.z), 0.f);
                r[3] = fmaxf(fmaf(v0.w, sc0.w, sh0.w), 0.f);
                r[4] = fmaxf(fmaf(v1.x, sc1.x, sh1.x), 0.f);
                r[5] = fmaxf(fmaf(v1.y, sc1.y, sh1.y), 0.f);
                r[6] = fmaxf(fmaf(v1.z, sc1.z, sh1.z), 0.f);
                r[7] = fmaxf(fmaf(v1.w, sc1.w, sh1.w), 0.f);
                if constexpr (MODE == 3) {
                    const uint4 pv = *(const uint4*)(hp + kk * 32);
                    r[0] = fmaf(sw, bflo(pv.x), r[0]); r[1] = fmaf(sw, bfhi(pv.x), r[1]);
                    r[2] = fmaf(sw, bflo(pv.y), r[2]); r[3] = fmaf(sw, bfhi(pv.y), r[3]);
                    r[4] = fmaf(sw, bflo(pv.z), r[4]); r[5] = fmaf(sw, bfhi(pv.z), r[5]);
                    r[6] = fmaf(sw, bflo(pv.w), r[6]); r[7] = fmaf(sw, bfhi(pv.w), r[7]);
                }
                uint4 o;
                o.x = pack2(r[0], r[1]);
                o.y = pack2(r[2], r[3]);
                o.z = pack2(r[4], r[5]);
                o.w = pack2(r[6], r[7]);
                a = *(const bf16x8*)&o;
                if constexpr (STOREH)
                    *(uint4*)&hout[(size_t)arow * 128 + k0] = o;
            }
        }
#pragma unroll
        for (int t = 0; t < NT; ++t) {
            bf16x8 b = *(const bf16x8*)(wp + t * 16 * 128 + kk * 32);
            acc[t] = __builtin_amdgcn_mfma_f32_16x16x32_bf16(a, b, acc[t], 0, 0, 0);
        }
    }
#pragma unroll
    for (int i = 0; i < 4; ++i) {
        const int row = rowbase + fq * 4 + i;
        if (row < n) {
#pragma unroll
            for (int t = 0; t < NT; ++t)
                O[(size_t)row * FOUT + t * 16 + fr] = f2bf(acc[t][i]);
        }
    }
}

// ---------------------------- aggregation ----------------------------------
// agg[d,f](f32) = sum_{e: dst=d} hW[src_e, f](bf16) * norm_e  (CSR by dst)
// PURE gather (R12/R13-proven): low VGPR -> high occupancy.

template <int F>
__global__ __launch_bounds__(256) void k_agg(const u16* __restrict__ hW,
                                             const uint2* __restrict__ csre,
                                             const int* __restrict__ offs,
                                             float* __restrict__ agg, int n) {
    constexpr int TPN = F / 8;       // lanes per node (16 or 8)
    constexpr int NPB = 256 / TPN;   // nodes per block (16 or 32)
    const int lane = threadIdx.x % TPN;
    const int sub = threadIdx.x / TPN;
    const int fbase = lane * 8;

    for (int node = blockIdx.x * NPB + sub; node < n; node += gridDim.x * NPB) {
        const int beg = offs[node];
        const int end = offs[node + 1];
        float4 b0 = make_float4(0.f, 0.f, 0.f, 0.f);
        float4 b1 = make_float4(0.f, 0.f, 0.f, 0.f);
        float4 c0 = make_float4(0.f, 0.f, 0.f, 0.f);
        float4 c1 = make_float4(0.f, 0.f, 0.f, 0.f);
        int j = beg;
        for (; j + 8 <= end; j += 8) {
            uint2 ei[8];
#pragma unroll
            for (int q = 0; q < 8; ++q) ei[q] = csre[j + q];
            uint4 v[8];
#pragma unroll
            for (int q = 0; q < 8; ++q)
                v[q] = *(const uint4*)&hW[(size_t)ei[q].x * F + fbase];
#pragma unroll
            for (int q = 0; q < 8; ++q) {
                const float w = __uint_as_float(ei[q].y);
                if (q & 1) {
                    c0.x = fmaf(bflo(v[q].x), w, c0.x); c0.y = fmaf(bfhi(v[q].x), w, c0.y);
                    c0.z = fmaf(bflo(v[q].y), w, c0.z); c0.w = fmaf(bfhi(v[q].y), w, c0.w);
                    c1.x = fmaf(bflo(v[q].z), w, c1.x); c1.y = fmaf(bfhi(v[q].z), w, c1.y);
                    c1.z = fmaf(bflo(v[q].w), w, c1.z); c1.w = fmaf(bfhi(v[q].w), w, c1.w);
                } else {
                    b0.x = fmaf(bflo(v[q].x), w, b0.x); b0.y = fmaf(bfhi(v[q].x), w, b0.y);
                    b0.z = fmaf(bflo(v[q].y), w, b0.z); b0.w = fmaf(bfhi(v[q].y), w, b0.w);
                    b1.x = fmaf(bflo(v[q].z), w, b1.x); b1.y = fmaf(bfhi(v[q].z), w, b1.y);
                    b1.z = fmaf(bflo(v[q].w), w, b1.z); b1.w = fmaf(bfhi(v[q].w), w, b1.w);
                }
            }
        }
        for (; j < end; ++j) {
            const uint2 e0 = csre[j];
            const float w = __uint_as_float(e0.y);
            const uint4 v0 = *(const uint4*)&hW[(size_t)e0.x * F + fbase];
            b0.x = fmaf(bflo(v0.x), w, b0.x); b0.y = fmaf(bfhi(v0.x), w, b0.y);
            b0.z = fmaf(bflo(v0.y), w, b0.z); b0.w = fmaf(bfhi(v0.y), w, b0.w);
            b1.x = fmaf(bflo(v0.z), w, b1.x); b1.y = fmaf(bfhi(v0.z), w, b1.y);
            b1.z = fmaf(bflo(v0.w), w, b1.z); b1.w = fmaf(bfhi(v0.w), w, b1.w);
        }
        b0.x += c0.x; b0.y += c0.y; b0.z += c0.z; b0.w += c0.w;
        b1.x += c1.x; b1.y += c1.y; b1.z += c1.z; b1.w += c1.w;
        __builtin_nontemporal_store(*(const f32x4*)&b0,
                                    (f32x4*)&agg[(size_t)node * F + fbase]);
        __builtin_nontemporal_store(*(const f32x4*)&b1,
                                    (f32x4*)&agg[(size_t)node * F + fbase + 4]);
    }
}

// --------------------- BN stats + coef (fused, ticketed) -------------------

template <int F>
__global__ __launch_bounds__(256) void k_stats(const float* __restrict__ aggf,
                                               float* __restrict__ stats,
                                               int* __restrict__ ticket,
                                               const float* __restrict__ g,
                                               const float* __restrict__ be,
                                               float* __restrict__ coef,
                                               float inv_n, int n8) {
    constexpr int TPR = F / 8;
    const int tid0 = blockIdx.x * 256 + threadIdx.x;
    float s[8], q[8];
#pragma unroll
    for (int k = 0; k < 8; ++k) { s[k] = 0.f; q[k] = 0.f; }
    for (int i = tid0; i < n8; i += gridDim.x * 256) {
        const float4 v0 = *(const float4*)&aggf[(size_t)i * 8];
        const float4 v1 = *(const float4*)&aggf[(size_t)i * 8 + 4];
        s[0] += v0.x; s[1] += v0.y; s[2] += v0.z; s[3] += v0.w;
        s[4] += v1.x; s[5] += v1.y; s[6] += v1.z; s[7] += v1.w;
        q[0] = fmaf(v0.x, v0.x, q[0]); q[1] = fmaf(v0.y, v0.y, q[1]);
        q[2] = fmaf(v0.z, v0.z, q[2]); q[3] = fmaf(v0.w, v0.w, q[3]);
        q[4] = fmaf(v1.x, v1.x, q[4]); q[5] = fmaf(v1.y, v1.y, q[5]);
        q[6] = fmaf(v1.z, v1.z, q[6]); q[7] = fmaf(v1.w, v1.w, q[7]);
    }
#pragma unroll
    for (int m = TPR; m < 64; m <<= 1) {
#pragma unroll
        for (int k = 0; k < 8; ++k) {
            s[k] += __shfl_xor(s[k], m);
            q[k] += __shfl_xor(q[k], m);
        }
    }
    __shared__ float sred[2][4][TPR * 8];
    const int w = threadIdx.x >> 6;
    const int l64 = threadIdx.x & 63;
    if (l64 < TPR) {
#pragma unroll
        for (int k = 0; k < 8; ++k) {
            sred[0][w][l64 * 8 + k] = s[k];
            sred[1][w][l64 * 8 + k] = q[k];
        }
    }
    __syncthreads();
    if (threadIdx.x < TPR * 8) {
        float a = sred[0][0][threadIdx.x] + sred[0][1][threadIdx.x] +
                  sred[0][2][threadIdx.x] + sred[0][3][threadIdx.x];
        float b = sred[1][0][threadIdx.x] + sred[1][1][threadIdx.x] +
                  sred[1][2][threadIdx.x] + sred[1][3][threadIdx.x];
        const int ff = threadIdx.x & (F - 1);
        atomicAdd(&stats[ff], a);
        atomicAdd(&stats[F + ff], b);
    }
    __threadfence();
    __shared__ int last;
    if (threadIdx.x == 0) last = (atomicAdd(ticket, 1) == (int)gridDim.x - 1) ? 1 : 0;
    __syncthreads();
    if (last) {
        if (threadIdx.x < F) {
            const int f = threadIdx.x;
            float sum = atomicAdd(&stats[f], 0.f);
            float ssq = atomicAdd(&stats[F + f], 0.f);
            float mean = sum * inv_n;
            float var = fmaxf(ssq * inv_n - mean * mean, 0.f);
            float sc = g[f] * rsqrtf(var + 1e-5f);
            coef[f] = sc;
            coef[F + f] = be[f] - mean * sc;
        }
    }
}

// ----------------------- layer-3 BN + mean pool -----------------------------

__global__ __launch_bounds__(256) void k_bnpool(const float* __restrict__ C,
                                                const int* __restrict__ batch,
                                                const float* __restrict__ coef,
                                                float* __restrict__ out, int n,
                                                int chunk) {
    __shared__ float pool[128 * 64];
    for (int i = threadIdx.x; i < 128 * 64; i += 256) pool[i] = 0.f;
    __syncthreads();
    const int f = threadIdx.x & 63;
    const int sub = threadIdx.x >> 6;
    const float sc = coef[f];
    const float sh = coef[64 + f];
    const int lo = blockIdx.x * chunk;
    int hi = lo + chunk; if (hi > n) hi = n;
    for (int node = lo + sub; node < hi; node += 4) {
        float v = fmaf(sc, C[(size_t)node * 64 + f], sh);
        int g = batch[node];
        atomicAdd(&pool[g * 64 + f], v);
    }
    __syncthreads();
    for (int i = threadIdx.x; i < 128 * 64; i += 256) {
        float v = pool[i];
        if (v != 0.f) atomicAdd(&out[i], v);
    }
}

__global__ void k_div(float* __restrict__ out, const int* __restrict__ gcnt, int total) {
    int i = blockIdx.x * blockDim.x + threadIdx.x;
    if (i < total) {
        int g = i >> 6;
        int c = gcnt[g];
        if (c < 1) c = 1;
        out[i] = out[i] / (float)c;
    }
}

// ------------------------------ launcher ------------------------------------

static inline size_t align256(size_t x) { return (x + 255) & ~(size_t)255; }

extern "C" void kernel_launch(void* const* d_in, const int* in_sizes, int n_in,
                              void* d_out, int out_size, void* d_ws, size_t ws_size,
                              hipStream_t stream) {
    const float* x    = (const float*)d_in[0];
    const int* ei     = (const int*)d_in[1];
    const int* batch  = (const int*)d_in[2];
    const float* W0   = (const float*)d_in[3];
    const float* g0   = (const float*)d_in[5];
    const float* be0  = (const float*)d_in[6];
    const float* W1   = (const float*)d_in[7];
    const float* g1   = (const float*)d_in[9];
    const float* be1  = (const float*)d_in[10];
    const float* W2   = (const float*)d_in[11];
    const float* g2   = (const float*)d_in[13];
    const float* be2  = (const float*)d_in[14];
    const float* W3   = (const float*)d_in[15];
    const float* g3   = (const float*)d_in[17];
    const float* be3  = (const float*)d_in[18];
    const float* swp  = (const float*)d_in[19];

    const int N = in_sizes[0] / 128;
    const int E = in_sizes[1] / 2;
    const int T = E + N;
    const int* esrc = ei;
    const int* edst = ei + E;

    char* p = (char*)d_ws;
    auto carve = [&](size_t bytes) -> char* {
        char* r = p;
        p += align256(bytes);
        return r;
    };
    int*   deg    = (int*)carve((size_t)N * 4);
    float* dinv   = (float*)carve((size_t)N * 4);
    int*   offs   = (int*)carve((size_t)(N + 1) * 4);
    int*   bsum   = (int*)carve(256 * 4);
    uint2* csre   = (uint2*)carve((size_t)T * 8);
    float* stats  = (float*)carve(4 * 256 * 4);
    float* coef   = (float*)carve(4 * 256 * 4);
    int*   ticket = (int*)carve(4 * 4);
    int*   gcnt   = (int*)carve(128 * 4);
    u16*   Wt0    = (u16*)carve(128 * 128 * 2);
    u16*   Wt1    = (u16*)carve(128 * 128 * 2);
    u16*   Wt2    = (u16*)carve(128 * 128 * 2);
    u16*   Wt3    = (u16*)carve(64 * 128 * 2);
    u16*   h0     = (u16*)carve((size_t)N * 128 * 2);
    u16*   h1     = (u16*)carve((size_t)N * 128 * 2);
    u16*   hWb    = (u16*)carve((size_t)N * 128 * 2);
    float* aggf   = (float*)carve((size_t)N * 128 * 4);

    hipMemsetAsync(deg, 0, (size_t)N * 4, stream);
    hipMemsetAsync(stats, 0, 4 * 256 * 4, stream);
    hipMemsetAsync(ticket, 0, 4 * 4, stream);
    hipMemsetAsync(d_out, 0, (size_t)out_size * 4, stream);

    // graph preprocessing
    const int EB = (E + 255) / 256;
    const int NB = (N + 255) / 256;
    const int B = (N + 1023) / 1024;
    k_deg<<<EB, 256, 0, stream>>>(edst, E, deg);
    k_dinv<<<NB, 256, 0, stream>>>(deg, N, dinv);
    k_bsum<<<B, 256, 0, stream>>>(deg, N, bsum);
    k_scanb<<<1, 1, 0, stream>>>(bsum, B);
    k_offs<<<B, 256, 0, stream>>>(deg, N, bsum, offs);
    k_fill_self<<<NB, 256, 0, stream>>>(N, dinv, offs, csre);
    k_fill_edges<<<EB, 256, 0, stream>>>(esrc, edst, E, dinv, offs, deg, csre);
    k_gcnt_bs<<<1, 128, 0, stream>>>(batch, N, gcnt);

    // weights -> bf16 transposed
    k_wt<128><<<1, 256, 0, stream>>>(W0, Wt0);
    k_wt<128><<<1, 256, 0, stream>>>(W1, Wt1);
    k_wt<128><<<1, 256, 0, stream>>>(W2, Wt2);
    k_wt<64><<<1, 256, 0, stream>>>(W3, Wt3);

    const float inv_n = 1.0f / (float)N;
    const int gemm_grid = (N + 63) / 64;
    const int chunk = (N + 255) / 256;
    const int n8_128 = N * 16;
    const int n8_64 = N * 8;

    // layer 0: x @ W0 (f32 in, cvt fused) -> agg -> stats+coef
    k_gemm_mfma<128, 1, false><<<gemm_grid, 256, 0, stream>>>(
        (const void*)x, nullptr, nullptr, nullptr, Wt0, nullptr, hWb, N);
    k_agg<128><<<2048, 256, 0, stream>>>(hWb, csre, offs, aggf, N);
    k_stats<128><<<256, 256, 0, stream>>>(aggf, stats + 0, ticket + 0, g0, be0,
                                          coef + 0, inv_n, n8_128);
    // layer 1: GEMM fuses bnapply_0 (no skip), stores h0; -> agg -> stats+coef
    k_gemm_mfma<128, 2, true><<<gemm_grid, 256, 0, stream>>>(
        (const void*)aggf, nullptr, coef + 0, nullptr, Wt1, h0, hWb, N);
    k_agg<128><<<2048, 256, 0, stream>>>(hWb, csre, offs, aggf, N);
    k_stats<128><<<256, 256, 0, stream>>>(aggf, stats + 256, ticket + 1, g1, be1,
                                          coef + 256, inv_n, n8_128);
    // layer 2: GEMM fuses bnapply_1 (skip from h0), stores h1; -> agg -> stats+coef
    k_gemm_mfma<128, 3, true><<<gemm_grid, 256, 0, stream>>>(
        (const void*)aggf, h0, coef + 256, swp, Wt2, h1, hWb, N);
    k_agg<128><<<2048, 256, 0, stream>>>(hWb, csre, offs, aggf, N);
    k_stats<128><<<256, 256, 0, stream>>>(aggf, stats + 512, ticket + 2, g2, be2,
                                          coef + 512, inv_n, n8_128);
    // layer 3: GEMM fuses bnapply_2 (skip from h1, no store); -> agg -> stats+coef
    k_gemm_mfma<64, 3, false><<<gemm_grid, 256, 0, stream>>>(
        (const void*)aggf, h1, coef + 512, swp, Wt3, nullptr, hWb, N);
    k_agg<64><<<2048, 256, 0, stream>>>(hWb, csre, offs, aggf, N);
    k_stats<64><<<256, 256, 0, stream>>>(aggf, stats + 768, ticket + 3, g3, be3,
                                         coef + 768, inv_n, n8_64);
    // BN + mean pool
    k_bnpool<<<256, 256, 0, stream>>>(aggf, batch, coef + 768, (float*)d_out, N, chunk);
    k_div<<<(out_size + 255) / 256, 256, 0, stream>>>((float*)d_out, gcnt, out_size);
}